// Round 1
// baseline (1259.426 us; speedup 1.0000x reference)
//
#include <hip/hip_runtime.h>
#include <hip/hip_bf16.h>
#include <stdint.h>

#define TOKENS 2048
#define HIDDEN 2048
#define INTER  1408
#define NEXP   8
#define TOPK   2
#define NPAIR  (TOKENS*TOPK)   // 4096

#define BM 64
#define BN 64
#define BK 64
#define SK 72   // padded LDS row stride (bf16 elems): 144 B -> 2-way bank alias only (free)

typedef __attribute__((ext_vector_type(8))) short bf16x8;
typedef __attribute__((ext_vector_type(4))) float f32x4;

static __device__ __forceinline__ unsigned short f2b(float f) {
    union { float f; uint32_t u; } v; v.f = f;
    uint32_t r = (v.u + 0x7FFFu + ((v.u >> 16) & 1u)) >> 16;   // RNE
    return (unsigned short)r;
}

// ---------------- routing: pack (token, weight) per expert ----------------
__global__ void route_k(const int* __restrict__ idx, const float* __restrict__ w,
                        int* __restrict__ off, int* __restrict__ tok,
                        float* __restrict__ wgt) {
    __shared__ int cnt[NEXP];
    __shared__ int cur[NEXP];
    int tid = threadIdx.x;
    if (tid < NEXP) cnt[tid] = 0;
    __syncthreads();
    for (int i = tid; i < NPAIR; i += 256) atomicAdd(&cnt[idx[i]], 1);
    __syncthreads();
    if (tid == 0) {
        int s = 0;
        for (int e = 0; e < NEXP; ++e) { off[e] = s; cur[e] = s; s += cnt[e]; }
        off[NEXP] = s;   // == NPAIR
    }
    __syncthreads();
    for (int i = tid; i < NPAIR; i += 256) {
        int e = idx[i];
        int p = atomicAdd(&cur[e], 1);
        tok[p] = i >> 1;       // token id (i / TOPK)
        wgt[p] = w[i];
    }
}

// ---------------- X fp32 -> bf16 ----------------
__global__ void conv_k(const float* __restrict__ x, unsigned short* __restrict__ xb, int n) {
    int i = (blockIdx.x * blockDim.x + threadIdx.x) * 4;
    if (i < n) {
        float4 v = *(const float4*)(x + i);
        ushort4 o;
        o.x = f2b(v.x); o.y = f2b(v.y); o.z = f2b(v.z); o.w = f2b(v.w);
        *(ushort4*)(xb + i) = o;
    }
}

// ---------------- GEMM1: gate+up fused, SwiGLU epilogue -> H (bf16) ----------------
__global__ __launch_bounds__(256, 2) void gemm1_k(
    const unsigned short* __restrict__ Xb,
    const float* __restrict__ Wg, const float* __restrict__ Wu,
    const int* __restrict__ off, const int* __restrict__ tok,
    unsigned short* __restrict__ H) {

    const int e    = blockIdx.z;
    const int o0   = off[e];
    const int cnt  = off[e + 1] - o0;
    const int row0 = blockIdx.x * BM;
    if (row0 >= cnt) return;
    const int col0 = blockIdx.y * BN;

    __shared__ __align__(16) unsigned short sA[BM * SK];
    __shared__ __align__(16) unsigned short sG[BN * SK];
    __shared__ __align__(16) unsigned short sU[BN * SK];
    __shared__ int stok[BM];

    const int tid = threadIdx.x;
    if (tid < BM) {
        int r = row0 + tid;
        stok[tid] = tok[o0 + (r < cnt ? r : 0)];
    }
    __syncthreads();

    f32x4 accg[2][2], accu[2][2];
    #pragma unroll
    for (int i = 0; i < 2; ++i)
        #pragma unroll
        for (int j = 0; j < 2; ++j) {
            accg[i][j] = (f32x4){0.f, 0.f, 0.f, 0.f};
            accu[i][j] = (f32x4){0.f, 0.f, 0.f, 0.f};
        }

    const int wave = tid >> 6;
    const int lane = tid & 63;
    const int wm   = (wave & 1) * 32;
    const int wn   = (wave >> 1) * 32;
    const int lm   = lane & 15;
    const int quad = lane >> 4;

    const float* wg_base = Wg + ((size_t)e * INTER + col0) * HIDDEN;
    const float* wu_base = Wu + ((size_t)e * INTER + col0) * HIDDEN;

    for (int k0 = 0; k0 < HIDDEN; k0 += BK) {
        // A: 64 rows x 8 segs of 8 bf16 (gathered token rows)
        #pragma unroll
        for (int s = tid; s < BM * 8; s += 256) {
            int r = s >> 3, c = (s & 7) * 8;
            int t = stok[r];
            *(int4*)&sA[r * SK + c] = *(const int4*)&Xb[(size_t)t * HIDDEN + k0 + c];
        }
        // Wg/Wu: 64 rows x 16 segs of 4 fp32 -> bf16 convert in-register
        #pragma unroll
        for (int s = tid; s < BN * 16; s += 256) {
            int r = s >> 4, c = (s & 15) * 4;
            float4 vg = *(const float4*)&wg_base[(size_t)r * HIDDEN + k0 + c];
            float4 vu = *(const float4*)&wu_base[(size_t)r * HIDDEN + k0 + c];
            ushort4 og; og.x = f2b(vg.x); og.y = f2b(vg.y); og.z = f2b(vg.z); og.w = f2b(vg.w);
            ushort4 ou; ou.x = f2b(vu.x); ou.y = f2b(vu.y); ou.z = f2b(vu.z); ou.w = f2b(vu.w);
            *(ushort4*)&sG[r * SK + c] = og;
            *(ushort4*)&sU[r * SK + c] = ou;
        }
        __syncthreads();
        #pragma unroll
        for (int kk = 0; kk < BK; kk += 32) {
            bf16x8 af[2], gf[2], uf[2];
            #pragma unroll
            for (int mi = 0; mi < 2; ++mi)
                af[mi] = *(const bf16x8*)&sA[(wm + mi * 16 + lm) * SK + kk + quad * 8];
            #pragma unroll
            for (int ni = 0; ni < 2; ++ni) {
                gf[ni] = *(const bf16x8*)&sG[(wn + ni * 16 + lm) * SK + kk + quad * 8];
                uf[ni] = *(const bf16x8*)&sU[(wn + ni * 16 + lm) * SK + kk + quad * 8];
            }
            #pragma unroll
            for (int mi = 0; mi < 2; ++mi)
                #pragma unroll
                for (int ni = 0; ni < 2; ++ni) {
                    accg[mi][ni] = __builtin_amdgcn_mfma_f32_16x16x32_bf16(af[mi], gf[ni], accg[mi][ni], 0, 0, 0);
                    accu[mi][ni] = __builtin_amdgcn_mfma_f32_16x16x32_bf16(af[mi], uf[ni], accu[mi][ni], 0, 0, 0);
                }
        }
        __syncthreads();
    }

    // epilogue: h = silu(g) * u -> bf16 H[pair][inter]
    #pragma unroll
    for (int mi = 0; mi < 2; ++mi) {
        #pragma unroll
        for (int reg = 0; reg < 4; ++reg) {
            int lr = wm + mi * 16 + quad * 4 + reg;   // C/D: row = quad*4+reg, col = lane&15
            int r  = row0 + lr;
            if (r < cnt) {
                size_t prow = (size_t)(o0 + r) * INTER;
                #pragma unroll
                for (int ni = 0; ni < 2; ++ni) {
                    float g = accg[mi][ni][reg];
                    float u = accu[mi][ni][reg];
                    float h = g / (1.f + __expf(-g)) * u;
                    H[prow + col0 + wn + ni * 16 + lm] = f2b(h);
                }
            }
        }
    }
}

// ---------------- GEMM2: down proj, weighted atomic combine into out ----------------
__global__ __launch_bounds__(256, 2) void gemm2_k(
    const unsigned short* __restrict__ H,
    const float* __restrict__ Wd,
    const int* __restrict__ off, const int* __restrict__ tok,
    const float* __restrict__ wgt,
    float* __restrict__ out) {

    const int e    = blockIdx.z;
    const int o0   = off[e];
    const int cnt  = off[e + 1] - o0;
    const int row0 = blockIdx.x * BM;
    if (row0 >= cnt) return;
    const int col0 = blockIdx.y * BN;

    __shared__ __align__(16) unsigned short sA[BM * SK];
    __shared__ __align__(16) unsigned short sB[BN * SK];
    __shared__ int   stok[BM];
    __shared__ float swgt[BM];

    const int tid = threadIdx.x;
    if (tid < BM) {
        int r  = row0 + tid;
        int rr = (r < cnt ? r : 0);
        stok[tid] = tok[o0 + rr];
        swgt[tid] = wgt[o0 + rr];
    }
    __syncthreads();

    f32x4 acc[2][2];
    #pragma unroll
    for (int i = 0; i < 2; ++i)
        #pragma unroll
        for (int j = 0; j < 2; ++j) acc[i][j] = (f32x4){0.f, 0.f, 0.f, 0.f};

    const int wave = tid >> 6;
    const int lane = tid & 63;
    const int wm   = (wave & 1) * 32;
    const int wn   = (wave >> 1) * 32;
    const int lm   = lane & 15;
    const int quad = lane >> 4;

    const float* wd_base = Wd + ((size_t)e * HIDDEN + col0) * INTER;

    for (int k0 = 0; k0 < INTER; k0 += BK) {
        #pragma unroll
        for (int s = tid; s < BM * 8; s += 256) {
            int r = s >> 3, c = (s & 7) * 8;
            int gr = row0 + r; if (gr >= cnt) gr = cnt - 1;
            *(int4*)&sA[r * SK + c] = *(const int4*)&H[(size_t)(o0 + gr) * INTER + k0 + c];
        }
        #pragma unroll
        for (int s = tid; s < BN * 16; s += 256) {
            int r = s >> 4, c = (s & 15) * 4;
            float4 v = *(const float4*)&wd_base[(size_t)r * INTER + k0 + c];
            ushort4 o; o.x = f2b(v.x); o.y = f2b(v.y); o.z = f2b(v.z); o.w = f2b(v.w);
            *(ushort4*)&sB[r * SK + c] = o;
        }
        __syncthreads();
        #pragma unroll
        for (int kk = 0; kk < BK; kk += 32) {
            bf16x8 af[2], bf[2];
            #pragma unroll
            for (int mi = 0; mi < 2; ++mi)
                af[mi] = *(const bf16x8*)&sA[(wm + mi * 16 + lm) * SK + kk + quad * 8];
            #pragma unroll
            for (int ni = 0; ni < 2; ++ni)
                bf[ni] = *(const bf16x8*)&sB[(wn + ni * 16 + lm) * SK + kk + quad * 8];
            #pragma unroll
            for (int mi = 0; mi < 2; ++mi)
                #pragma unroll
                for (int ni = 0; ni < 2; ++ni)
                    acc[mi][ni] = __builtin_amdgcn_mfma_f32_16x16x32_bf16(af[mi], bf[ni], acc[mi][ni], 0, 0, 0);
        }
        __syncthreads();
    }

    #pragma unroll
    for (int mi = 0; mi < 2; ++mi) {
        #pragma unroll
        for (int reg = 0; reg < 4; ++reg) {
            int lr = wm + mi * 16 + quad * 4 + reg;
            int r  = row0 + lr;
            if (r < cnt) {
                int   t = stok[lr];
                float w = swgt[lr];
                #pragma unroll
                for (int ni = 0; ni < 2; ++ni) {
                    atomicAdd(&out[(size_t)t * HIDDEN + col0 + wn + ni * 16 + lm],
                              w * acc[mi][ni][reg]);
                }
            }
        }
    }
}

extern "C" void kernel_launch(void* const* d_in, const int* in_sizes, int n_in,
                              void* d_out, int out_size, void* d_ws, size_t ws_size,
                              hipStream_t stream) {
    const float* X   = (const float*)d_in[0];
    const int*   idx = (const int*)d_in[1];
    const float* tw  = (const float*)d_in[2];
    const float* Wg  = (const float*)d_in[3];
    const float* Wu  = (const float*)d_in[4];
    const float* Wd  = (const float*)d_in[5];
    float* out = (float*)d_out;

    char* ws = (char*)d_ws;
    int*            off = (int*)ws;                                   // 9 ints
    int*            tok = (int*)(ws + 64);                            // 4096 ints
    float*          wgt = (float*)(ws + 64 + NPAIR * 4);              // 4096 floats
    unsigned short* Xb  = (unsigned short*)(ws + 65536);              // 8 MB
    unsigned short* H   = (unsigned short*)(ws + 65536 + (size_t)TOKENS * HIDDEN * 2); // 11.5 MB

    hipMemsetAsync(d_out, 0, (size_t)out_size * sizeof(float), stream);

    route_k<<<1, 256, 0, stream>>>(idx, tw, off, tok, wgt);
    conv_k<<<(TOKENS * HIDDEN / 4 + 255) / 256, 256, 0, stream>>>(X, Xb, TOKENS * HIDDEN);
    gemm1_k<<<dim3(NPAIR / BM, INTER / BN, NEXP), 256, 0, stream>>>(Xb, Wg, Wu, off, tok, H);
    gemm2_k<<<dim3(NPAIR / BM, HIDDEN / BN, NEXP), 256, 0, stream>>>(H, Wd, off, tok, wgt, out);
}

// Round 2
// 1014.193 us; speedup vs baseline: 1.2418x; 1.2418x over previous
//
#include <hip/hip_runtime.h>
#include <hip/hip_bf16.h>
#include <stdint.h>

#define TOKENS 2048
#define HIDDEN 2048
#define INTER  1408
#define NEXP   8
#define TOPK   2
#define NPAIR  (TOKENS*TOPK)   // 4096

// fallback (round-1) tile params
#define BM 64
#define BN 64
#define BK 64
#define SK 72

typedef __attribute__((ext_vector_type(8))) short bf16x8;
typedef __attribute__((ext_vector_type(4))) float f32x4;

static __device__ __forceinline__ unsigned short f2b(float f) {
    union { float f; uint32_t u; } v; v.f = f;
    uint32_t r = (v.u + 0x7FFFu + ((v.u >> 16) & 1u)) >> 16;   // RNE
    return (unsigned short)r;
}

// async global->LDS, 16B per lane; global addr is per-lane (gather OK),
// LDS dest is wave-uniform base + lane*16.
static __device__ __forceinline__ void gload_lds16(const void* g, void* l) {
    __builtin_amdgcn_global_load_lds(
        (const __attribute__((address_space(1))) void*)g,
        (__attribute__((address_space(3))) void*)l,
        16, 0, 0);
}

// ---------------- routing: pack (token, weight) per expert ----------------
__global__ void route_k(const int* __restrict__ idx, const float* __restrict__ w,
                        int* __restrict__ off, int* __restrict__ tok,
                        float* __restrict__ wgt) {
    __shared__ int cnt[NEXP];
    __shared__ int cur[NEXP];
    int tid = threadIdx.x;
    if (tid < NEXP) cnt[tid] = 0;
    __syncthreads();
    for (int i = tid; i < NPAIR; i += 256) atomicAdd(&cnt[idx[i]], 1);
    __syncthreads();
    if (tid == 0) {
        int s = 0;
        for (int e = 0; e < NEXP; ++e) { off[e] = s; cur[e] = s; s += cnt[e]; }
        off[NEXP] = s;
    }
    __syncthreads();
    for (int i = tid; i < NPAIR; i += 256) {
        int e = idx[i];
        int p = atomicAdd(&cur[e], 1);
        tok[p] = i >> 1;
        wgt[p] = w[i];
    }
}

// ---------------- fp32 -> bf16 bulk convert ----------------
__global__ void conv_k(const float* __restrict__ x, unsigned short* __restrict__ xb, int n) {
    int i = (blockIdx.x * blockDim.x + threadIdx.x) * 4;
    if (i < n) {
        float4 v = *(const float4*)(x + i);
        ushort4 o;
        o.x = f2b(v.x); o.y = f2b(v.y); o.z = f2b(v.z); o.w = f2b(v.w);
        *(ushort4*)(xb + i) = o;
    }
}

// =================== bf16-weight fast path ===================
// GEMM1: [cnt x 2048] x [1408 x 2048]^T (gate,up) -> silu(g)*u -> H bf16
// block: 256 thr (4 waves), tile 128(M) x 64(N), BK=64
__global__ __launch_bounds__(256, 3) void gemm1b_k(
    const unsigned short* __restrict__ Xb,
    const unsigned short* __restrict__ Wgb, const unsigned short* __restrict__ Wub,
    const int* __restrict__ off, const int* __restrict__ tok,
    unsigned short* __restrict__ H) {

    const int e    = blockIdx.z;
    const int o0   = off[e];
    const int cnt  = off[e + 1] - o0;
    const int row0 = blockIdx.x * 128;
    if (row0 >= cnt) return;
    const int col0 = blockIdx.y * 64;

    __shared__ __align__(16) unsigned short sA[128 * 64];
    __shared__ __align__(16) unsigned short sG[64 * 64];
    __shared__ __align__(16) unsigned short sU[64 * 64];
    __shared__ int stok[128];

    const int tid = threadIdx.x;
    if (tid < 128) {
        int r = row0 + tid;
        stok[tid] = tok[o0 + (r < cnt ? r : cnt - 1)];
    }
    __syncthreads();

    const int wave = tid >> 6, lane = tid & 63;
    const int wr = wave >> 1, wc = wave & 1;
    const int lm = lane & 15, quad = lane >> 4;
    const int lrow8 = lane >> 3;        // 0..7 (row within 8-row issue)
    const int lseg  = (lane & 7) * 8;   // elem offset within row

    // per-lane invariant global sources + wave-uniform LDS dests
    const unsigned short* gA[4]; unsigned short* lA[4];
    #pragma unroll
    for (int j = 0; j < 4; ++j) {
        int rl = wave * 32 + j * 8 + lrow8;
        gA[j] = Xb + (size_t)stok[rl] * HIDDEN + lseg;
        lA[j] = &sA[(wave * 32 + j * 8) * 64];
    }
    const unsigned short* gG[2]; const unsigned short* gU[2];
    unsigned short* lG[2]; unsigned short* lU[2];
    #pragma unroll
    for (int j = 0; j < 2; ++j) {
        int rl = wave * 16 + j * 8 + lrow8;
        gG[j] = Wgb + ((size_t)e * INTER + col0 + rl) * HIDDEN + lseg;
        gU[j] = Wub + ((size_t)e * INTER + col0 + rl) * HIDDEN + lseg;
        lG[j] = &sG[(wave * 16 + j * 8) * 64];
        lU[j] = &sU[(wave * 16 + j * 8) * 64];
    }

    f32x4 accg[4][2], accu[4][2];
    #pragma unroll
    for (int i = 0; i < 4; ++i)
        #pragma unroll
        for (int j = 0; j < 2; ++j) {
            accg[i][j] = (f32x4){0.f, 0.f, 0.f, 0.f};
            accu[i][j] = (f32x4){0.f, 0.f, 0.f, 0.f};
        }

    for (int k0 = 0; k0 < HIDDEN; k0 += 64) {
        #pragma unroll
        for (int j = 0; j < 4; ++j) gload_lds16(gA[j] + k0, lA[j]);
        #pragma unroll
        for (int j = 0; j < 2; ++j) {
            gload_lds16(gG[j] + k0, lG[j]);
            gload_lds16(gU[j] + k0, lU[j]);
        }
        __syncthreads();
        #pragma unroll
        for (int kk = 0; kk < 64; kk += 32) {
            bf16x8 af[4], gf[2], uf[2];
            #pragma unroll
            for (int mi = 0; mi < 4; ++mi)
                af[mi] = *(const bf16x8*)&sA[(wr * 64 + mi * 16 + lm) * 64 + kk + quad * 8];
            #pragma unroll
            for (int ni = 0; ni < 2; ++ni) {
                gf[ni] = *(const bf16x8*)&sG[(wc * 32 + ni * 16 + lm) * 64 + kk + quad * 8];
                uf[ni] = *(const bf16x8*)&sU[(wc * 32 + ni * 16 + lm) * 64 + kk + quad * 8];
            }
            #pragma unroll
            for (int mi = 0; mi < 4; ++mi)
                #pragma unroll
                for (int ni = 0; ni < 2; ++ni) {
                    accg[mi][ni] = __builtin_amdgcn_mfma_f32_16x16x32_bf16(af[mi], gf[ni], accg[mi][ni], 0, 0, 0);
                    accu[mi][ni] = __builtin_amdgcn_mfma_f32_16x16x32_bf16(af[mi], uf[ni], accu[mi][ni], 0, 0, 0);
                }
        }
        __syncthreads();
    }

    #pragma unroll
    for (int mi = 0; mi < 4; ++mi) {
        #pragma unroll
        for (int reg = 0; reg < 4; ++reg) {
            int lr = wr * 64 + mi * 16 + quad * 4 + reg;
            int r  = row0 + lr;
            if (r < cnt) {
                size_t hrow = (size_t)(o0 + r) * INTER;
                #pragma unroll
                for (int ni = 0; ni < 2; ++ni) {
                    float g = accg[mi][ni][reg];
                    float u = accu[mi][ni][reg];
                    float h = g / (1.f + __expf(-g)) * u;
                    H[hrow + col0 + wc * 32 + ni * 16 + lm] = f2b(h);
                }
            }
        }
    }
}

// GEMM2: [cnt x 1408] x [2048 x 1408]^T -> weighted atomic scatter into out
__global__ __launch_bounds__(256, 3) void gemm2b_k(
    const unsigned short* __restrict__ H,
    const unsigned short* __restrict__ Wdb,
    const int* __restrict__ off, const int* __restrict__ tok,
    const float* __restrict__ wgt,
    float* __restrict__ out) {

    const int e    = blockIdx.z;
    const int o0   = off[e];
    const int cnt  = off[e + 1] - o0;
    const int row0 = blockIdx.x * 128;
    if (row0 >= cnt) return;
    const int col0 = blockIdx.y * 64;

    __shared__ __align__(16) unsigned short sA[128 * 64];
    __shared__ __align__(16) unsigned short sB[64 * 64];
    __shared__ int   stok[128];
    __shared__ float swgt[128];

    const int tid = threadIdx.x;
    if (tid < 128) {
        int r  = row0 + tid;
        int rr = (r < cnt ? r : cnt - 1);
        stok[tid] = tok[o0 + rr];
        swgt[tid] = wgt[o0 + rr];
    }
    __syncthreads();

    const int wave = tid >> 6, lane = tid & 63;
    const int wr = wave >> 1, wc = wave & 1;
    const int lm = lane & 15, quad = lane >> 4;
    const int lrow8 = lane >> 3;
    const int lseg  = (lane & 7) * 8;

    const unsigned short* gA[4]; unsigned short* lA[4];
    #pragma unroll
    for (int j = 0; j < 4; ++j) {
        int rl = wave * 32 + j * 8 + lrow8;
        int gr = row0 + rl; if (gr >= cnt) gr = cnt - 1;
        gA[j] = H + (size_t)(o0 + gr) * INTER + lseg;
        lA[j] = &sA[(wave * 32 + j * 8) * 64];
    }
    const unsigned short* gB[2]; unsigned short* lB[2];
    #pragma unroll
    for (int j = 0; j < 2; ++j) {
        int rl = wave * 16 + j * 8 + lrow8;
        gB[j] = Wdb + ((size_t)e * HIDDEN + col0 + rl) * INTER + lseg;
        lB[j] = &sB[(wave * 16 + j * 8) * 64];
    }

    f32x4 acc[4][2];
    #pragma unroll
    for (int i = 0; i < 4; ++i)
        #pragma unroll
        for (int j = 0; j < 2; ++j) acc[i][j] = (f32x4){0.f, 0.f, 0.f, 0.f};

    for (int k0 = 0; k0 < INTER; k0 += 64) {
        #pragma unroll
        for (int j = 0; j < 4; ++j) gload_lds16(gA[j] + k0, lA[j]);
        #pragma unroll
        for (int j = 0; j < 2; ++j) gload_lds16(gB[j] + k0, lB[j]);
        __syncthreads();
        #pragma unroll
        for (int kk = 0; kk < 64; kk += 32) {
            bf16x8 af[4], bf[2];
            #pragma unroll
            for (int mi = 0; mi < 4; ++mi)
                af[mi] = *(const bf16x8*)&sA[(wr * 64 + mi * 16 + lm) * 64 + kk + quad * 8];
            #pragma unroll
            for (int ni = 0; ni < 2; ++ni)
                bf[ni] = *(const bf16x8*)&sB[(wc * 32 + ni * 16 + lm) * 64 + kk + quad * 8];
            #pragma unroll
            for (int mi = 0; mi < 4; ++mi)
                #pragma unroll
                for (int ni = 0; ni < 2; ++ni)
                    acc[mi][ni] = __builtin_amdgcn_mfma_f32_16x16x32_bf16(af[mi], bf[ni], acc[mi][ni], 0, 0, 0);
        }
        __syncthreads();
    }

    #pragma unroll
    for (int mi = 0; mi < 4; ++mi) {
        #pragma unroll
        for (int reg = 0; reg < 4; ++reg) {
            int lr = wr * 64 + mi * 16 + quad * 4 + reg;
            int r  = row0 + lr;
            if (r < cnt) {
                int   t = stok[lr];
                float w = swgt[lr];
                #pragma unroll
                for (int ni = 0; ni < 2; ++ni)
                    atomicAdd(&out[(size_t)t * HIDDEN + col0 + wc * 32 + ni * 16 + lm],
                              w * acc[mi][ni][reg]);
            }
        }
    }
}

// =================== fallback (round-1) fp32-weight path ===================
__global__ __launch_bounds__(256, 2) void gemm1_fb(
    const unsigned short* __restrict__ Xb,
    const float* __restrict__ Wg, const float* __restrict__ Wu,
    const int* __restrict__ off, const int* __restrict__ tok,
    unsigned short* __restrict__ H) {

    const int e    = blockIdx.z;
    const int o0   = off[e];
    const int cnt  = off[e + 1] - o0;
    const int row0 = blockIdx.x * BM;
    if (row0 >= cnt) return;
    const int col0 = blockIdx.y * BN;

    __shared__ __align__(16) unsigned short sA[BM * SK];
    __shared__ __align__(16) unsigned short sG[BN * SK];
    __shared__ __align__(16) unsigned short sU[BN * SK];
    __shared__ int stok[BM];

    const int tid = threadIdx.x;
    if (tid < BM) {
        int r = row0 + tid;
        stok[tid] = tok[o0 + (r < cnt ? r : 0)];
    }
    __syncthreads();

    f32x4 accg[2][2], accu[2][2];
    #pragma unroll
    for (int i = 0; i < 2; ++i)
        #pragma unroll
        for (int j = 0; j < 2; ++j) {
            accg[i][j] = (f32x4){0.f, 0.f, 0.f, 0.f};
            accu[i][j] = (f32x4){0.f, 0.f, 0.f, 0.f};
        }

    const int wave = tid >> 6;
    const int lane = tid & 63;
    const int wm   = (wave & 1) * 32;
    const int wn   = (wave >> 1) * 32;
    const int lm   = lane & 15;
    const int quad = lane >> 4;

    const float* wg_base = Wg + ((size_t)e * INTER + col0) * HIDDEN;
    const float* wu_base = Wu + ((size_t)e * INTER + col0) * HIDDEN;

    for (int k0 = 0; k0 < HIDDEN; k0 += BK) {
        #pragma unroll
        for (int s = tid; s < BM * 8; s += 256) {
            int r = s >> 3, c = (s & 7) * 8;
            int t = stok[r];
            *(int4*)&sA[r * SK + c] = *(const int4*)&Xb[(size_t)t * HIDDEN + k0 + c];
        }
        #pragma unroll
        for (int s = tid; s < BN * 16; s += 256) {
            int r = s >> 4, c = (s & 15) * 4;
            float4 vg = *(const float4*)&wg_base[(size_t)r * HIDDEN + k0 + c];
            float4 vu = *(const float4*)&wu_base[(size_t)r * HIDDEN + k0 + c];
            ushort4 og; og.x = f2b(vg.x); og.y = f2b(vg.y); og.z = f2b(vg.z); og.w = f2b(vg.w);
            ushort4 ou; ou.x = f2b(vu.x); ou.y = f2b(vu.y); ou.z = f2b(vu.z); ou.w = f2b(vu.w);
            *(ushort4*)&sG[r * SK + c] = og;
            *(ushort4*)&sU[r * SK + c] = ou;
        }
        __syncthreads();
        #pragma unroll
        for (int kk = 0; kk < BK; kk += 32) {
            bf16x8 af[2], gf[2], uf[2];
            #pragma unroll
            for (int mi = 0; mi < 2; ++mi)
                af[mi] = *(const bf16x8*)&sA[(wm + mi * 16 + lm) * SK + kk + quad * 8];
            #pragma unroll
            for (int ni = 0; ni < 2; ++ni) {
                gf[ni] = *(const bf16x8*)&sG[(wn + ni * 16 + lm) * SK + kk + quad * 8];
                uf[ni] = *(const bf16x8*)&sU[(wn + ni * 16 + lm) * SK + kk + quad * 8];
            }
            #pragma unroll
            for (int mi = 0; mi < 2; ++mi)
                #pragma unroll
                for (int ni = 0; ni < 2; ++ni) {
                    accg[mi][ni] = __builtin_amdgcn_mfma_f32_16x16x32_bf16(af[mi], gf[ni], accg[mi][ni], 0, 0, 0);
                    accu[mi][ni] = __builtin_amdgcn_mfma_f32_16x16x32_bf16(af[mi], uf[ni], accu[mi][ni], 0, 0, 0);
                }
        }
        __syncthreads();
    }

    #pragma unroll
    for (int mi = 0; mi < 2; ++mi) {
        #pragma unroll
        for (int reg = 0; reg < 4; ++reg) {
            int lr = wm + mi * 16 + quad * 4 + reg;
            int r  = row0 + lr;
            if (r < cnt) {
                size_t prow = (size_t)(o0 + r) * INTER;
                #pragma unroll
                for (int ni = 0; ni < 2; ++ni) {
                    float g = accg[mi][ni][reg];
                    float u = accu[mi][ni][reg];
                    float h = g / (1.f + __expf(-g)) * u;
                    H[prow + col0 + wn + ni * 16 + lm] = f2b(h);
                }
            }
        }
    }
}

__global__ __launch_bounds__(256, 2) void gemm2_fb(
    const unsigned short* __restrict__ H,
    const float* __restrict__ Wd,
    const int* __restrict__ off, const int* __restrict__ tok,
    const float* __restrict__ wgt,
    float* __restrict__ out) {

    const int e    = blockIdx.z;
    const int o0   = off[e];
    const int cnt  = off[e + 1] - o0;
    const int row0 = blockIdx.x * BM;
    if (row0 >= cnt) return;
    const int col0 = blockIdx.y * BN;

    __shared__ __align__(16) unsigned short sA[BM * SK];
    __shared__ __align__(16) unsigned short sB[BN * SK];
    __shared__ int   stok[BM];
    __shared__ float swgt[BM];

    const int tid = threadIdx.x;
    if (tid < BM) {
        int r  = row0 + tid;
        int rr = (r < cnt ? r : 0);
        stok[tid] = tok[o0 + rr];
        swgt[tid] = wgt[o0 + rr];
    }
    __syncthreads();

    f32x4 acc[2][2];
    #pragma unroll
    for (int i = 0; i < 2; ++i)
        #pragma unroll
        for (int j = 0; j < 2; ++j) acc[i][j] = (f32x4){0.f, 0.f, 0.f, 0.f};

    const int wave = tid >> 6;
    const int lane = tid & 63;
    const int wm   = (wave & 1) * 32;
    const int wn   = (wave >> 1) * 32;
    const int lm   = lane & 15;
    const int quad = lane >> 4;

    const float* wd_base = Wd + ((size_t)e * HIDDEN + col0) * INTER;

    for (int k0 = 0; k0 < INTER; k0 += BK) {
        #pragma unroll
        for (int s = tid; s < BM * 8; s += 256) {
            int r = s >> 3, c = (s & 7) * 8;
            int gr = row0 + r; if (gr >= cnt) gr = cnt - 1;
            *(int4*)&sA[r * SK + c] = *(const int4*)&H[(size_t)(o0 + gr) * INTER + k0 + c];
        }
        #pragma unroll
        for (int s = tid; s < BN * 16; s += 256) {
            int r = s >> 4, c = (s & 15) * 4;
            float4 v = *(const float4*)&wd_base[(size_t)r * INTER + k0 + c];
            ushort4 o; o.x = f2b(v.x); o.y = f2b(v.y); o.z = f2b(v.z); o.w = f2b(v.w);
            *(ushort4*)&sB[r * SK + c] = o;
        }
        __syncthreads();
        #pragma unroll
        for (int kk = 0; kk < BK; kk += 32) {
            bf16x8 af[2], bf[2];
            #pragma unroll
            for (int mi = 0; mi < 2; ++mi)
                af[mi] = *(const bf16x8*)&sA[(wm + mi * 16 + lm) * SK + kk + quad * 8];
            #pragma unroll
            for (int ni = 0; ni < 2; ++ni)
                bf[ni] = *(const bf16x8*)&sB[(wn + ni * 16 + lm) * SK + kk + quad * 8];
            #pragma unroll
            for (int mi = 0; mi < 2; ++mi)
                #pragma unroll
                for (int ni = 0; ni < 2; ++ni)
                    acc[mi][ni] = __builtin_amdgcn_mfma_f32_16x16x32_bf16(af[mi], bf[ni], acc[mi][ni], 0, 0, 0);
        }
        __syncthreads();
    }

    #pragma unroll
    for (int mi = 0; mi < 2; ++mi) {
        #pragma unroll
        for (int reg = 0; reg < 4; ++reg) {
            int lr = wm + mi * 16 + quad * 4 + reg;
            int r  = row0 + lr;
            if (r < cnt) {
                int   t = stok[lr];
                float w = swgt[lr];
                #pragma unroll
                for (int ni = 0; ni < 2; ++ni) {
                    atomicAdd(&out[(size_t)t * HIDDEN + col0 + wn + ni * 16 + lm],
                              w * acc[mi][ni][reg]);
                }
            }
        }
    }
}

extern "C" void kernel_launch(void* const* d_in, const int* in_sizes, int n_in,
                              void* d_out, int out_size, void* d_ws, size_t ws_size,
                              hipStream_t stream) {
    const float* X   = (const float*)d_in[0];
    const int*   idx = (const int*)d_in[1];
    const float* tw  = (const float*)d_in[2];
    const float* Wg  = (const float*)d_in[3];
    const float* Wu  = (const float*)d_in[4];
    const float* Wd  = (const float*)d_in[5];
    float* out = (float*)d_out;

    char* ws = (char*)d_ws;
    // layout
    const size_t OFF_TOK = 64;
    const size_t OFF_WGT = 64 + (size_t)NPAIR * 4;
    const size_t OFF_XB  = 65536;
    const size_t OFF_H   = OFF_XB + (size_t)TOKENS * HIDDEN * 2;           // 8 MB Xb
    const size_t WELEMS  = (size_t)NEXP * INTER * HIDDEN;                  // 23.07M
    const size_t OFF_WG  = OFF_H + (size_t)NPAIR * INTER * 2;              // 11.5 MB H
    const size_t OFF_WU  = OFF_WG + WELEMS * 2;
    const size_t OFF_WD  = OFF_WU + WELEMS * 2;
    const size_t WS_NEED = OFF_WD + WELEMS * 2;                            // ~158.4 MB

    int*            off = (int*)ws;
    int*            tok = (int*)(ws + OFF_TOK);
    float*          wgt = (float*)(ws + OFF_WGT);
    unsigned short* Xb  = (unsigned short*)(ws + OFF_XB);
    unsigned short* H   = (unsigned short*)(ws + OFF_H);
    unsigned short* Wgb = (unsigned short*)(ws + OFF_WG);
    unsigned short* Wub = (unsigned short*)(ws + OFF_WU);
    unsigned short* Wdb = (unsigned short*)(ws + OFF_WD);

    hipMemsetAsync(d_out, 0, (size_t)out_size * sizeof(float), stream);

    route_k<<<1, 256, 0, stream>>>(idx, tw, off, tok, wgt);
    conv_k<<<(TOKENS * HIDDEN / 4 + 255) / 256, 256, 0, stream>>>(X, Xb, TOKENS * HIDDEN);

    if (ws_size >= WS_NEED) {
        const int wn4 = (int)(WELEMS / 4);
        conv_k<<<(wn4 + 255) / 256, 256, 0, stream>>>(Wg, Wgb, (int)WELEMS);
        conv_k<<<(wn4 + 255) / 256, 256, 0, stream>>>(Wu, Wub, (int)WELEMS);
        conv_k<<<(wn4 + 255) / 256, 256, 0, stream>>>(Wd, Wdb, (int)WELEMS);
        gemm1b_k<<<dim3(NPAIR / 128, INTER / 64, NEXP), 256, 0, stream>>>(Xb, Wgb, Wub, off, tok, H);
        gemm2b_k<<<dim3(NPAIR / 128, HIDDEN / 64, NEXP), 256, 0, stream>>>(H, Wdb, off, tok, wgt, out);
    } else {
        gemm1_fb<<<dim3(NPAIR / BM, INTER / BN, NEXP), 256, 0, stream>>>(Xb, Wg, Wu, off, tok, H);
        gemm2_fb<<<dim3(NPAIR / BM, HIDDEN / BN, NEXP), 256, 0, stream>>>(H, Wd, off, tok, wgt, out);
    }
}